// Round 1
// baseline (266.712 us; speedup 1.0000x reference)
//
#include <hip/hip_runtime.h>
#include <math.h>

#define TT 4096
#define BB 32
#define DD 128
#define HH 256
#define KL 64
#define DM 1024
#define KEFF 64
#define KBUDGET 16.0f
#define LAM_ 0.5f

// ---------------------------------------------------------------------------
// Kernel 1: saliency[b,t] = softplus( tanh(x@W1 + b1) @ w_s )
// 64 rows per block, 256 threads (4 waves). W1 staged in 64-h chunks, natural
// [d][h] layout (conflict-free staging + 2-way-max read conflicts, which are
// free on CDNA4). Per-lane 4row x 4h register tile: 8 ds_read_b128 per 64 FMA.
// ---------------------------------------------------------------------------
__global__ __launch_bounds__(256, 2) void k_sal(const float* __restrict__ x,
    const float* __restrict__ W1, const float* __restrict__ b1,
    const float* __restrict__ w_s, float* __restrict__ sal_out)
{
  __shared__ float xs[64][DD + 4];   // +4 pad: row groups land in distinct banks
  __shared__ float w1s[DD][64];

  const int tid = threadIdx.x;
  const long rowbase = (long)blockIdx.x * 64;

  // stage x tile: 64 rows x 128 f32 (2048 float4, coalesced)
  {
    const float4* xg = (const float4*)(x + rowbase * DD);
    #pragma unroll
    for (int it = 0; it < 8; ++it) {
      int i = tid + it * 256;
      int r = i >> 5, c4 = i & 31;
      float4 v = xg[i];
      *(float4*)&xs[r][c4 * 4] = v;
    }
  }

  const int lane = tid & 63;
  const int wave = tid >> 6;
  const int hq = lane & 15;          // 16 h-groups of 4 consecutive h
  const int rq = lane >> 4;          // 4 row-groups of 4 rows
  const int rb = wave * 16 + rq * 4; // this lane's local row base

  float s_acc[4] = {0.f, 0.f, 0.f, 0.f};

  for (int c = 0; c < HH / 64; ++c) {
    __syncthreads();
    // stage W1 chunk [128][64], natural layout, coalesced read+write
    #pragma unroll
    for (int it = 0; it < 8; ++it) {
      int i = tid + it * 256;        // 2048 float4s
      int h4 = i & 15, d = i >> 4;
      float4 v = *(const float4*)&W1[d * HH + c * 64 + h4 * 4];
      *(float4*)&w1s[d][h4 * 4] = v;
    }
    __syncthreads();

    float acc[4][4];
    #pragma unroll
    for (int i = 0; i < 4; ++i)
      #pragma unroll
      for (int j = 0; j < 4; ++j) acc[i][j] = 0.f;

    #pragma unroll 2
    for (int d4 = 0; d4 < DD / 4; ++d4) {
      float4 xv0 = *(const float4*)&xs[rb + 0][d4 * 4];
      float4 xv1 = *(const float4*)&xs[rb + 1][d4 * 4];
      float4 xv2 = *(const float4*)&xs[rb + 2][d4 * 4];
      float4 xv3 = *(const float4*)&xs[rb + 3][d4 * 4];
      float4 wv0 = *(const float4*)&w1s[d4 * 4 + 0][hq * 4];
      float4 wv1 = *(const float4*)&w1s[d4 * 4 + 1][hq * 4];
      float4 wv2 = *(const float4*)&w1s[d4 * 4 + 2][hq * 4];
      float4 wv3 = *(const float4*)&w1s[d4 * 4 + 3][hq * 4];
#define ROWFMA(I, XV)                                  \
      acc[I][0] = fmaf(XV.x, wv0.x, acc[I][0]);        \
      acc[I][1] = fmaf(XV.x, wv0.y, acc[I][1]);        \
      acc[I][2] = fmaf(XV.x, wv0.z, acc[I][2]);        \
      acc[I][3] = fmaf(XV.x, wv0.w, acc[I][3]);        \
      acc[I][0] = fmaf(XV.y, wv1.x, acc[I][0]);        \
      acc[I][1] = fmaf(XV.y, wv1.y, acc[I][1]);        \
      acc[I][2] = fmaf(XV.y, wv1.z, acc[I][2]);        \
      acc[I][3] = fmaf(XV.y, wv1.w, acc[I][3]);        \
      acc[I][0] = fmaf(XV.z, wv2.x, acc[I][0]);        \
      acc[I][1] = fmaf(XV.z, wv2.y, acc[I][1]);        \
      acc[I][2] = fmaf(XV.z, wv2.z, acc[I][2]);        \
      acc[I][3] = fmaf(XV.z, wv2.w, acc[I][3]);        \
      acc[I][0] = fmaf(XV.w, wv3.x, acc[I][0]);        \
      acc[I][1] = fmaf(XV.w, wv3.y, acc[I][1]);        \
      acc[I][2] = fmaf(XV.w, wv3.z, acc[I][2]);        \
      acc[I][3] = fmaf(XV.w, wv3.w, acc[I][3]);
      ROWFMA(0, xv0)
      ROWFMA(1, xv1)
      ROWFMA(2, xv2)
      ROWFMA(3, xv3)
#undef ROWFMA
    }

    const int h0 = c * 64 + hq * 4;
    #pragma unroll
    for (int j = 0; j < 4; ++j) {
      float bj = b1[h0 + j];
      float wsj = w_s[h0 + j];
      #pragma unroll
      for (int i = 0; i < 4; ++i) {
        float t = tanhf(acc[i][j] + bj);
        s_acc[i] = fmaf(t, wsj, s_acc[i]);
      }
    }
  }

  // reduce the per-lane partial (16 h-columns each) across the 16 hq lanes
  #pragma unroll
  for (int m = 1; m < 16; m <<= 1) {
    #pragma unroll
    for (int i = 0; i < 4; ++i) s_acc[i] += __shfl_xor(s_acc[i], m, 64);
  }
  if (hq == 0) {
    #pragma unroll
    for (int i = 0; i < 4; ++i) {
      float z = s_acc[i];
      float sp = fmaxf(z, 0.f) + log1pf(expf(-fabsf(z)));  // stable softplus
      sal_out[rowbase + rb + i] = sp;
    }
  }
}

// ---------------------------------------------------------------------------
// Kernel 2: per-batch selector. Reads saliency (staged in the y_star region),
// computes y_star (writes it back), inclusive cumsum of saliency, and exact
// jax.lax.top_k top-64 (desc value, ties -> lower index). Stores selected
// (idx, saliency, cumsum) triples in ws for kernel 3.
// ---------------------------------------------------------------------------
__global__ __launch_bounds__(256) void k_sel(const float* __restrict__ logt,
    float* __restrict__ ysr, int* __restrict__ topidx,
    float* __restrict__ topsal, float* __restrict__ topcums)
{
  __shared__ float sal[TT];
  __shared__ float ya[TT];   // y (pre-refractory), then reused as cumsum
  __shared__ float yb[TT];   // y_star
  __shared__ float redf[8];
  __shared__ int   redi[8];

  const int tid = threadIdx.x;
  const int lane = tid & 63;
  const int wave = tid >> 6;
  const int b = blockIdx.x;
  float* row = ysr + (long)b * TT;

  for (int i = tid; i < TT; i += 256) sal[i] = row[i];
  __syncthreads();

  float temp = expf(logt[0]);
  temp = fminf(fmaxf(temp, 0.1f), 10.f);
  const float inv2lam = 1.0f / (2.0f * LAM_);

  for (int i = tid; i < TT; i += 256) {
    float z = (sal[i] * inv2lam - 0.5f) / temp;
    float s;
    if (z >= 0.f) { float e = expf(-z); s = 1.f / (1.f + e); }
    else          { float e = expf(z);  s = e / (1.f + e); }
    ya[i] = (i == 0) ? 0.f : s;
  }
  __syncthreads();

  // budget = sum(y); scale = min(K/max(budget,1e-6), 1)
  float loc = 0.f;
  for (int i = tid; i < TT; i += 256) loc += ya[i];
  #pragma unroll
  for (int m = 1; m < 64; m <<= 1) loc += __shfl_xor(loc, m, 64);
  if (lane == 0) redf[wave] = loc;
  __syncthreads();
  float budget = redf[0] + redf[1] + redf[2] + redf[3];
  float scale = fminf(KBUDGET / fmaxf(budget, 1e-6f), 1.f);

  // refractory (d=1, wraps): y'[t] = ys[t]*min(2/(1+ys[t]+ys[t+1]),1)
  for (int i = tid; i < TT; i += 256) {
    float yi = ya[i] * scale;
    float yj = ya[(i + 1) & (TT - 1)] * scale;
    float m = fminf(2.f / (1.f + (yi + yj)), 1.f);
    yb[i] = (i == 0) ? 0.f : yi * m;
  }
  __syncthreads();

  for (int i = tid; i < TT; i += 256) row[i] = yb[i];   // y_star out

  // inclusive cumsum of saliency into ya (16 local + wave scan + wave offsets)
  const int base = tid * 16;
  float run = 0.f;
  #pragma unroll
  for (int j = 0; j < 16; ++j) { run += sal[base + j]; ya[base + j] = run; }
  float v = run;
  #pragma unroll
  for (int m = 1; m < 64; m <<= 1) {
    float u = __shfl_up(v, (unsigned)m, 64);
    if (lane >= m) v += u;
  }
  float lexcl = v - run;
  if (lane == 63) redf[4 + wave] = v;
  __syncthreads();
  float woff = 0.f;
  for (int w = 0; w < wave; ++w) woff += redf[4 + w];
  float off = woff + lexcl;
  #pragma unroll
  for (int j = 0; j < 16; ++j) ya[base + j] += off;
  __syncthreads();

  // iterative top-64: per-thread candidates live in registers, removal via
  // bitmask (no runtime-indexed register arrays -> no scratch)
  float lv[16];
  #pragma unroll
  for (int j = 0; j < 16; ++j) lv[j] = yb[base + j];
  unsigned rm = 0;
  float bv = -1.f; int bi = 1 << 30;
  #pragma unroll
  for (int j = 0; j < 16; ++j)
    if (!((rm >> j) & 1u) && lv[j] > bv) { bv = lv[j]; bi = base + j; }

  for (int it = 0; it < KEFF; ++it) {
    float cv = bv; int ci = bi;
    #pragma unroll
    for (int m = 1; m < 64; m <<= 1) {
      float ov = __shfl_xor(cv, m, 64);
      int   oi = __shfl_xor(ci, m, 64);
      if (ov > cv || (ov == cv && oi < ci)) { cv = ov; ci = oi; }
    }
    if (lane == 0) { redf[wave] = cv; redi[wave] = ci; }
    __syncthreads();
    float wv_ = redf[0]; int wi_ = redi[0];
    #pragma unroll
    for (int w = 1; w < 4; ++w)
      if (redf[w] > wv_ || (redf[w] == wv_ && redi[w] < wi_)) { wv_ = redf[w]; wi_ = redi[w]; }
    if (tid == 0) {
      topidx[b * KEFF + it]  = wi_;
      topsal[b * KEFF + it]  = sal[wi_];
      topcums[b * KEFF + it] = ya[wi_];
    }
    if (wi_ >= base && wi_ < base + 16) {
      rm |= 1u << (wi_ - base);
      bv = -1.f; bi = 1 << 30;
      #pragma unroll
      for (int j = 0; j < 16; ++j)
        if (!((rm >> j) & 1u) && lv[j] > bv) { bv = lv[j]; bi = base + j; }
    }
    __syncthreads();
  }
}

// ---------------------------------------------------------------------------
// Kernel 3: lift + L2-normalize + project, only for the 2048 selected anchors.
// 256 blocks (8 anchors each), 256 threads. Lift: one wave per anchor-slot,
// lane k owns one lifted dim; norm via shfl. Projection: coalesced W_proj.
// ---------------------------------------------------------------------------
__global__ __launch_bounds__(256) void k_tok(const float* __restrict__ x,
    const float* __restrict__ W_lift, const float* __restrict__ b_lift,
    const float* __restrict__ W_proj, const float* __restrict__ b_proj,
    const int* __restrict__ topidx, const float* __restrict__ topsal,
    const float* __restrict__ topcums, float* __restrict__ tokens)
{
  __shared__ float cloud[8][KL];
  const int tid = threadIdx.x;
  const int k = tid & 63;
  const int g = tid >> 6;
  const int b = blockIdx.x >> 3;
  const int nb = (blockIdx.x & 7) * 8;

  #pragma unroll
  for (int a = 0; a < 2; ++a) {
    int n = nb + g + a * 4;
    int t = topidx[b * KEFF + n];
    const float* xr = x + ((long)b * TT + t) * DD;
    float acc = 0.f;
    #pragma unroll 8
    for (int d4 = 0; d4 < DD / 4; ++d4) {
      float4 xv = *(const float4*)&xr[d4 * 4];
      acc = fmaf(xv.x, W_lift[(d4 * 4 + 0) * KL + k], acc);
      acc = fmaf(xv.y, W_lift[(d4 * 4 + 1) * KL + k], acc);
      acc = fmaf(xv.z, W_lift[(d4 * 4 + 2) * KL + k], acc);
      acc = fmaf(xv.w, W_lift[(d4 * 4 + 3) * KL + k], acc);
    }
    float s  = topsal[b * KEFF + n];
    float tp = (float)t / (float)TT;
    float cm = topcums[b * KEFF + n];
    acc = fmaf(s,  W_lift[128 * KL + k], acc);
    acc = fmaf(tp, W_lift[129 * KL + k], acc);
    acc = fmaf(cm, W_lift[130 * KL + k], acc);
    acc += b_lift[k];
    float ss = acc * acc;
    #pragma unroll
    for (int m = 1; m < 64; m <<= 1) ss += __shfl_xor(ss, m, 64);
    float denom = fmaxf(sqrtf(ss), 1e-6f);
    cloud[g + a * 4][k] = acc / denom;
  }
  __syncthreads();

  #pragma unroll
  for (int q = 0; q < 4; ++q) {
    int dcol = tid + q * 256;
    float accp[8];
    #pragma unroll
    for (int n = 0; n < 8; ++n) accp[n] = 0.f;
    for (int kk = 0; kk < KL; ++kk) {
      float w = W_proj[kk * DM + dcol];
      #pragma unroll
      for (int n = 0; n < 8; ++n) accp[n] = fmaf(cloud[n][kk], w, accp[n]);
    }
    float bp = b_proj[dcol];
    #pragma unroll
    for (int n = 0; n < 8; ++n)
      tokens[((long)b * KEFF + nb + n) * DM + dcol] = accp[n] + bp;
  }
}

extern "C" void kernel_launch(void* const* d_in, const int* in_sizes, int n_in,
                              void* d_out, int out_size, void* d_ws, size_t ws_size,
                              hipStream_t stream) {
  const float* x      = (const float*)d_in[0];
  const float* W1     = (const float*)d_in[1];
  const float* b1     = (const float*)d_in[2];
  // d_in[3] = w_e: event_scores are unused downstream -> skipped entirely
  const float* w_s    = (const float*)d_in[4];
  const float* W_lift = (const float*)d_in[5];
  const float* b_lift = (const float*)d_in[6];
  const float* W_proj = (const float*)d_in[7];
  const float* b_proj = (const float*)d_in[8];
  const float* logt   = (const float*)d_in[9];

  float* tokens = (float*)d_out;
  float* ysr    = tokens + (size_t)BB * KEFF * DM;   // y_star region (also
                                                     // scratch for saliency)
  int*   topidx  = (int*)d_ws;
  float* topsal  = (float*)((char*)d_ws + 8192);
  float* topcums = (float*)((char*)d_ws + 16384);

  k_sal<<<(BB * TT) / 64, 256, 0, stream>>>(x, W1, b1, w_s, ysr);
  k_sel<<<BB, 256, 0, stream>>>(logt, ysr, topidx, topsal, topcums);
  k_tok<<<BB * 8, 256, 0, stream>>>(x, W_lift, b_lift, W_proj, b_proj,
                                    topidx, topsal, topcums, tokens);
}

// Round 2
// 261.002 us; speedup vs baseline: 1.0219x; 1.0219x over previous
//
#include <hip/hip_runtime.h>
#include <math.h>

#define TT 4096
#define BB 32
#define DD 128
#define HH 256
#define KL 64
#define DM 1024
#define KEFF 64
#define KBUDGET 16.0f
#define LAM_ 0.5f

// fast tanh: 1 - 2/(1+exp2(x*2*log2e)); hw v_exp_f32 + v_rcp_f32 (~6 insts).
// |err| ~1e-6 abs; attenuated to ~2e-9 in y* -> far below rank-64 gaps (~1e-6).
__device__ __forceinline__ float fast_tanh(float x) {
#if __has_builtin(__builtin_amdgcn_exp2f)
  float e = __builtin_amdgcn_exp2f(x * 2.885390081777927f);
#else
  float e = __expf(2.0f * x);
#endif
  float r = __builtin_amdgcn_rcpf(e + 1.0f);
  return fmaf(-2.0f, r, 1.0f);
}

// ---------------------------------------------------------------------------
// Kernel 1: saliency[b,t] = softplus( tanh(x@W1 + b1) @ w_s )
// Block: 64 rows x 256 h, 256 threads (4 waves as 2 row-halves x 2 h-halves).
// Loop: hc (2 h-chunks of 128) x ds (2 d-slabs of 64). LDS 50KB -> 3 blk/CU.
// Per-lane tile 4 rows x 8 h; rows rq+8i so x-reads hit 8 distinct bank quads.
// 12 ds_read_b128 per 128 FMAs.
// ---------------------------------------------------------------------------
__global__ __launch_bounds__(256, 3) void k_sal(const float* __restrict__ x,
    const float* __restrict__ W1, const float* __restrict__ b1,
    const float* __restrict__ w_s, float* __restrict__ sal_out)
{
  __shared__ float xs[64][68];      // 17.4 KB (stride 68: conflict-free reads)
  __shared__ float w1s[64][128];    // 32 KB
  __shared__ float redsm[2][64];

  const int tid  = threadIdx.x;
  const int lane = tid & 63;
  const int wave = tid >> 6;
  const int wr = wave & 1;          // row half (32 rows)
  const int wh = wave >> 1;         // h half (64 of the 128-chunk)
  const int rq = lane >> 3;         // 0..7
  const int hq = lane & 7;          // 0..7
  const long rowbase = (long)blockIdx.x * 64;

  float s_acc[4] = {0.f, 0.f, 0.f, 0.f};

  for (int hc = 0; hc < 2; ++hc) {
    float acc[4][8];
    #pragma unroll
    for (int i = 0; i < 4; ++i)
      #pragma unroll
      for (int j = 0; j < 8; ++j) acc[i][j] = 0.f;

    for (int ds = 0; ds < 2; ++ds) {
      __syncthreads();
      // stage x slab: 64 rows x 64 d  (1024 float4)
      #pragma unroll
      for (int p = 0; p < 4; ++p) {
        int i = tid + p * 256;
        int r = i >> 4, c4 = i & 15;
        float4 v = *(const float4*)&x[(rowbase + r) * DD + ds * 64 + c4 * 4];
        *(float4*)&xs[r][c4 * 4] = v;
      }
      // stage W1 slab: 64 d x 128 h  (2048 float4)
      #pragma unroll
      for (int p = 0; p < 8; ++p) {
        int i = tid + p * 256;
        int h4 = i & 31, d = i >> 5;
        float4 v = *(const float4*)&W1[(ds * 64 + d) * HH + hc * 128 + h4 * 4];
        *(float4*)&w1s[d][h4 * 4] = v;
      }
      __syncthreads();

      const int rbase = wr * 32 + rq;      // rows rbase + 8*i
      const int hbase = wh * 64 + hq * 8;  // 8 h columns

      #pragma unroll 4
      for (int d4 = 0; d4 < 16; ++d4) {
        float4 xv0 = *(const float4*)&xs[rbase +  0][d4 * 4];
        float4 xv1 = *(const float4*)&xs[rbase +  8][d4 * 4];
        float4 xv2 = *(const float4*)&xs[rbase + 16][d4 * 4];
        float4 xv3 = *(const float4*)&xs[rbase + 24][d4 * 4];
        #pragma unroll
        for (int d = 0; d < 4; ++d) {
          float4 wa = *(const float4*)&w1s[d4 * 4 + d][hbase];
          float4 wb = *(const float4*)&w1s[d4 * 4 + d][hbase + 4];
          float xd0 = (d == 0) ? xv0.x : (d == 1) ? xv0.y : (d == 2) ? xv0.z : xv0.w;
          float xd1 = (d == 0) ? xv1.x : (d == 1) ? xv1.y : (d == 2) ? xv1.z : xv1.w;
          float xd2 = (d == 0) ? xv2.x : (d == 1) ? xv2.y : (d == 2) ? xv2.z : xv2.w;
          float xd3 = (d == 0) ? xv3.x : (d == 1) ? xv3.y : (d == 2) ? xv3.z : xv3.w;
#define COLFMA(I, XD)                              \
          acc[I][0] = fmaf(XD, wa.x, acc[I][0]);   \
          acc[I][1] = fmaf(XD, wa.y, acc[I][1]);   \
          acc[I][2] = fmaf(XD, wa.z, acc[I][2]);   \
          acc[I][3] = fmaf(XD, wa.w, acc[I][3]);   \
          acc[I][4] = fmaf(XD, wb.x, acc[I][4]);   \
          acc[I][5] = fmaf(XD, wb.y, acc[I][5]);   \
          acc[I][6] = fmaf(XD, wb.z, acc[I][6]);   \
          acc[I][7] = fmaf(XD, wb.w, acc[I][7]);
          COLFMA(0, xd0)
          COLFMA(1, xd1)
          COLFMA(2, xd2)
          COLFMA(3, xd3)
#undef COLFMA
        }
      }
    }

    // epilogue for this h-chunk: tanh + weighted sum into s_acc
    const int h0 = hc * 128 + wh * 64 + hq * 8;
    #pragma unroll
    for (int j = 0; j < 8; ++j) {
      float bj  = b1[h0 + j];
      float wsj = w_s[h0 + j];
      #pragma unroll
      for (int i = 0; i < 4; ++i) {
        float t = fast_tanh(acc[i][j] + bj);
        s_acc[i] = fmaf(t, wsj, s_acc[i]);
      }
    }
  }

  // reduce across the 8 hq lanes (xor 1,2,4 stays within the hq field)
  #pragma unroll
  for (int m = 1; m < 8; m <<= 1) {
    #pragma unroll
    for (int i = 0; i < 4; ++i) s_acc[i] += __shfl_xor(s_acc[i], m, 64);
  }
  if (hq == 0) {
    #pragma unroll
    for (int i = 0; i < 4; ++i) redsm[wh][wr * 32 + rq + 8 * i] = s_acc[i];
  }
  __syncthreads();
  if (tid < 64) {
    float z = redsm[0][tid] + redsm[1][tid];
    float sp = fmaxf(z, 0.f) + log1pf(expf(-fabsf(z)));  // stable softplus
    sal_out[rowbase + tid] = sp;
  }
}

// ---------------------------------------------------------------------------
// Kernel 2: per-batch selector. Reads saliency (staged in the y_star region),
// computes y_star (writes it back), inclusive cumsum of saliency, and exact
// jax.lax.top_k top-64 (desc value, ties -> lower index). Top-64 runs in a
// single wave (no __syncthreads in the 64-iteration loop).
// ---------------------------------------------------------------------------
__global__ __launch_bounds__(256) void k_sel(const float* __restrict__ logt,
    float* __restrict__ ysr, int* __restrict__ topidx,
    float* __restrict__ topsal, float* __restrict__ topcums)
{
  __shared__ float sal[TT];
  __shared__ float ya[TT];   // y (pre-refractory), then reused as cumsum
  __shared__ float yb[TT];   // y_star
  __shared__ float redf[8];

  const int tid = threadIdx.x;
  const int lane = tid & 63;
  const int wave = tid >> 6;
  const int b = blockIdx.x;
  float* row = ysr + (long)b * TT;

  for (int i = tid; i < TT; i += 256) sal[i] = row[i];
  __syncthreads();

  float temp = expf(logt[0]);
  temp = fminf(fmaxf(temp, 0.1f), 10.f);
  const float inv2lam = 1.0f / (2.0f * LAM_);

  for (int i = tid; i < TT; i += 256) {
    float z = (sal[i] * inv2lam - 0.5f) / temp;
    float s;
    if (z >= 0.f) { float e = expf(-z); s = 1.f / (1.f + e); }
    else          { float e = expf(z);  s = e / (1.f + e); }
    ya[i] = (i == 0) ? 0.f : s;
  }
  __syncthreads();

  // budget = sum(y); scale = min(K/max(budget,1e-6), 1)
  float loc = 0.f;
  for (int i = tid; i < TT; i += 256) loc += ya[i];
  #pragma unroll
  for (int m = 1; m < 64; m <<= 1) loc += __shfl_xor(loc, m, 64);
  if (lane == 0) redf[wave] = loc;
  __syncthreads();
  float budget = redf[0] + redf[1] + redf[2] + redf[3];
  float scale = fminf(KBUDGET / fmaxf(budget, 1e-6f), 1.f);

  // refractory (d=1, wraps): y'[t] = ys[t]*min(2/(1+ys[t]+ys[t+1]),1)
  for (int i = tid; i < TT; i += 256) {
    float yi = ya[i] * scale;
    float yj = ya[(i + 1) & (TT - 1)] * scale;
    float m = fminf(2.f / (1.f + (yi + yj)), 1.f);
    yb[i] = (i == 0) ? 0.f : yi * m;
  }
  __syncthreads();

  for (int i = tid; i < TT; i += 256) row[i] = yb[i];   // y_star out

  // inclusive cumsum of saliency into ya (16 local + wave scan + wave offsets)
  const int base = tid * 16;
  float run = 0.f;
  #pragma unroll
  for (int j = 0; j < 16; ++j) { run += sal[base + j]; ya[base + j] = run; }
  float v = run;
  #pragma unroll
  for (int m = 1; m < 64; m <<= 1) {
    float u = __shfl_up(v, (unsigned)m, 64);
    if (lane >= m) v += u;
  }
  float lexcl = v - run;
  if (lane == 63) redf[4 + wave] = v;
  __syncthreads();
  float woff = 0.f;
  for (int w = 0; w < wave; ++w) woff += redf[4 + w];
  float off = woff + lexcl;
  #pragma unroll
  for (int j = 0; j < 16; ++j) ya[base + j] += off;
  __syncthreads();

  // single-wave exact top-64: lane owns 64 contiguous slots of yb; removal by
  // sentinel (-1; all y* >= 0). No barriers inside the loop.
  if (wave == 0) {
    const int b2 = lane * 64;
    float bv = -1.f; int bi = 1 << 30;
    for (int j = 0; j < 64; ++j) {
      float vv = yb[b2 + j];
      if (vv > bv) { bv = vv; bi = b2 + j; }
    }
    for (int it = 0; it < KEFF; ++it) {
      float cv = bv; int ci = bi;
      #pragma unroll
      for (int m = 1; m < 64; m <<= 1) {
        float ov = __shfl_xor(cv, m, 64);
        int   oi = __shfl_xor(ci, m, 64);
        if (ov > cv || (ov == cv && oi < ci)) { cv = ov; ci = oi; }
      }
      if (lane == 0) {
        topidx[b * KEFF + it]  = ci;
        topsal[b * KEFF + it]  = sal[ci];
        topcums[b * KEFF + it] = ya[ci];
      }
      if (ci >= b2 && ci < b2 + 64) {
        yb[ci] = -1.f;
        bv = -1.f; bi = 1 << 30;
        for (int j = 0; j < 64; ++j) {
          float vv = yb[b2 + j];
          if (vv > bv) { bv = vv; bi = b2 + j; }
        }
      }
    }
  }
}

// ---------------------------------------------------------------------------
// Kernel 3: lift + L2-normalize + project for the 2048 selected anchors.
// 128 blocks x 16 anchors, 256 threads. Lift: one wave per anchor slot (4
// passes), lane k owns one lifted dim; norm via shfl. Projection coalesced.
// ---------------------------------------------------------------------------
__global__ __launch_bounds__(256) void k_tok(const float* __restrict__ x,
    const float* __restrict__ W_lift, const float* __restrict__ b_lift,
    const float* __restrict__ W_proj, const float* __restrict__ b_proj,
    const int* __restrict__ topidx, const float* __restrict__ topsal,
    const float* __restrict__ topcums, float* __restrict__ tokens)
{
  __shared__ float cloud[16][KL];
  const int tid = threadIdx.x;
  const int k = tid & 63;
  const int g = tid >> 6;
  const int b = blockIdx.x >> 2;
  const int nb = (blockIdx.x & 3) * 16;

  #pragma unroll
  for (int a = 0; a < 4; ++a) {
    int n = nb + g + a * 4;
    int t = topidx[b * KEFF + n];
    const float* xr = x + ((long)b * TT + t) * DD;
    float acc = 0.f;
    #pragma unroll 8
    for (int d4 = 0; d4 < DD / 4; ++d4) {
      float4 xv = *(const float4*)&xr[d4 * 4];
      acc = fmaf(xv.x, W_lift[(d4 * 4 + 0) * KL + k], acc);
      acc = fmaf(xv.y, W_lift[(d4 * 4 + 1) * KL + k], acc);
      acc = fmaf(xv.z, W_lift[(d4 * 4 + 2) * KL + k], acc);
      acc = fmaf(xv.w, W_lift[(d4 * 4 + 3) * KL + k], acc);
    }
    float s  = topsal[b * KEFF + n];
    float tp = (float)t / (float)TT;
    float cm = topcums[b * KEFF + n];
    acc = fmaf(s,  W_lift[128 * KL + k], acc);
    acc = fmaf(tp, W_lift[129 * KL + k], acc);
    acc = fmaf(cm, W_lift[130 * KL + k], acc);
    acc += b_lift[k];
    float ss = acc * acc;
    #pragma unroll
    for (int m = 1; m < 64; m <<= 1) ss += __shfl_xor(ss, m, 64);
    float denom = fmaxf(sqrtf(ss), 1e-6f);
    cloud[g + a * 4][k] = acc / denom;
  }
  __syncthreads();

  #pragma unroll
  for (int q = 0; q < 4; ++q) {
    int dcol = tid + q * 256;
    float accp[16];
    #pragma unroll
    for (int n = 0; n < 16; ++n) accp[n] = 0.f;
    #pragma unroll 4
    for (int kk = 0; kk < KL; ++kk) {
      float w = W_proj[kk * DM + dcol];
      #pragma unroll
      for (int n = 0; n < 16; ++n) accp[n] = fmaf(cloud[n][kk], w, accp[n]);
    }
    float bp = b_proj[dcol];
    #pragma unroll
    for (int n = 0; n < 16; ++n)
      tokens[((long)b * KEFF + nb + n) * DM + dcol] = accp[n] + bp;
  }
}

extern "C" void kernel_launch(void* const* d_in, const int* in_sizes, int n_in,
                              void* d_out, int out_size, void* d_ws, size_t ws_size,
                              hipStream_t stream) {
  const float* x      = (const float*)d_in[0];
  const float* W1     = (const float*)d_in[1];
  const float* b1     = (const float*)d_in[2];
  // d_in[3] = w_e: event_scores are unused downstream -> skipped entirely
  const float* w_s    = (const float*)d_in[4];
  const float* W_lift = (const float*)d_in[5];
  const float* b_lift = (const float*)d_in[6];
  const float* W_proj = (const float*)d_in[7];
  const float* b_proj = (const float*)d_in[8];
  const float* logt   = (const float*)d_in[9];

  float* tokens = (float*)d_out;
  float* ysr    = tokens + (size_t)BB * KEFF * DM;   // y_star region (also
                                                     // scratch for saliency)
  int*   topidx  = (int*)d_ws;
  float* topsal  = (float*)((char*)d_ws + 8192);
  float* topcums = (float*)((char*)d_ws + 16384);

  k_sal<<<(BB * TT) / 64, 256, 0, stream>>>(x, W1, b1, w_s, ysr);
  k_sel<<<BB, 256, 0, stream>>>(logt, ysr, topidx, topsal, topcums);
  k_tok<<<BB * 4, 256, 0, stream>>>(x, W_lift, b_lift, W_proj, b_proj,
                                    topidx, topsal, topcums, tokens);
}

// Round 5
// 235.252 us; speedup vs baseline: 1.1337x; 1.1095x over previous
//
#include <hip/hip_runtime.h>
#include <math.h>

#define TT 4096
#define BB 32
#define DD 128
#define HH 256
#define KL 64
#define DM 1024
#define KEFF 64
#define KBUDGET 16.0f
#define LAM_ 0.5f

// fast tanh: 1 - 2/(1+exp2(x*2*log2e)); hw v_exp_f32 + v_rcp_f32 (~6 insts).
__device__ __forceinline__ float fast_tanh(float x) {
#if __has_builtin(__builtin_amdgcn_exp2f)
  float e = __builtin_amdgcn_exp2f(x * 2.885390081777927f);
#else
  float e = __expf(2.0f * x);
#endif
  float r = __builtin_amdgcn_rcpf(e + 1.0f);
  return fmaf(-2.0f, r, 1.0f);
}

// ---------------------------------------------------------------------------
// Kernel 1: saliency[b,t] = softplus( tanh(x@W1 + b1) @ w_s )
// 64 rows/block, 256 threads. x staged ONCE in LDS ([64][132], conflict-free
// row-group reads); W1 streamed from L1/L2 (coalesced 256B/wave per d-row).
// Wave = 8 row-groups x 8 h-groups; lane tile 8 rows x 8 h (acc[8][8]).
// 2 barriers per block; 8 ds_read_b128 + 8 dwordx4 per 256 FMA instructions.
// ---------------------------------------------------------------------------
__global__ __launch_bounds__(256, 3) void k_sal(const float* __restrict__ x,
    const float* __restrict__ W1, const float* __restrict__ b1,
    const float* __restrict__ w_s, float* __restrict__ sal_out)
{
  __shared__ float xs[64][132];     // 33792 B; row stride 132 -> rq rows hit
                                    // distinct bank quads on b128 reads
  __shared__ float redsm[4][64];

  const int tid  = threadIdx.x;
  const int lane = tid & 63;
  const int wave = tid >> 6;
  const int rq = lane & 7;          // row group: rows rq + 8i
  const int hq = lane >> 3;         // 0..7, 8 h each
  const int h0 = wave * 64 + hq * 8;
  const long rowbase = (long)blockIdx.x * 64;

  // stage x tile: 64 rows x 128 d (2048 float4, coalesced)
  #pragma unroll
  for (int p = 0; p < 8; ++p) {
    int i = tid + p * 256;
    int r = i >> 5, c4 = i & 31;
    float4 v = *(const float4*)&x[(rowbase + r) * DD + c4 * 4];
    *(float4*)&xs[r][c4 * 4] = v;
  }
  __syncthreads();

  float acc[8][8];
  #pragma unroll
  for (int i = 0; i < 8; ++i)
    #pragma unroll
    for (int j = 0; j < 8; ++j) acc[i][j] = 0.f;

  const float* __restrict__ Wb = W1 + h0;

#define FMAROW(I, XD, WA, WB)                      \
  acc[I][0] = fmaf(XD, WA.x, acc[I][0]);           \
  acc[I][1] = fmaf(XD, WA.y, acc[I][1]);           \
  acc[I][2] = fmaf(XD, WA.z, acc[I][2]);           \
  acc[I][3] = fmaf(XD, WA.w, acc[I][3]);           \
  acc[I][4] = fmaf(XD, WB.x, acc[I][4]);           \
  acc[I][5] = fmaf(XD, WB.y, acc[I][5]);           \
  acc[I][6] = fmaf(XD, WB.z, acc[I][6]);           \
  acc[I][7] = fmaf(XD, WB.w, acc[I][7]);
#define FMAD(C, WA, WB)                            \
  FMAROW(0, xv0.C, WA, WB)                         \
  FMAROW(1, xv1.C, WA, WB)                         \
  FMAROW(2, xv2.C, WA, WB)                         \
  FMAROW(3, xv3.C, WA, WB)                         \
  FMAROW(4, xv4.C, WA, WB)                         \
  FMAROW(5, xv5.C, WA, WB)                         \
  FMAROW(6, xv6.C, WA, WB)                         \
  FMAROW(7, xv7.C, WA, WB)

  #pragma unroll 2
  for (int d4 = 0; d4 < DD / 4; ++d4) {
    float4 xv0 = *(const float4*)&xs[rq +  0][d4 * 4];
    float4 xv1 = *(const float4*)&xs[rq +  8][d4 * 4];
    float4 xv2 = *(const float4*)&xs[rq + 16][d4 * 4];
    float4 xv3 = *(const float4*)&xs[rq + 24][d4 * 4];
    float4 xv4 = *(const float4*)&xs[rq + 32][d4 * 4];
    float4 xv5 = *(const float4*)&xs[rq + 40][d4 * 4];
    float4 xv6 = *(const float4*)&xs[rq + 48][d4 * 4];
    float4 xv7 = *(const float4*)&xs[rq + 56][d4 * 4];
    const float* wp = Wb + (d4 * 4) * HH;
    float4 wa0 = *(const float4*)&wp[0];
    float4 wb0 = *(const float4*)&wp[4];
    float4 wa1 = *(const float4*)&wp[HH];
    float4 wb1 = *(const float4*)&wp[HH + 4];
    float4 wa2 = *(const float4*)&wp[2 * HH];
    float4 wb2 = *(const float4*)&wp[2 * HH + 4];
    float4 wa3 = *(const float4*)&wp[3 * HH];
    float4 wb3 = *(const float4*)&wp[3 * HH + 4];
    FMAD(x, wa0, wb0)
    FMAD(y, wa1, wb1)
    FMAD(z, wa2, wb2)
    FMAD(w, wa3, wb3)
  }
#undef FMAD
#undef FMAROW

  // epilogue: tanh + w_s dot over this lane's 8 h columns
  float4 ba  = *(const float4*)&b1[h0];
  float4 bb  = *(const float4*)&b1[h0 + 4];
  float4 wsa = *(const float4*)&w_s[h0];
  float4 wsb = *(const float4*)&w_s[h0 + 4];
  float s_acc[8];
  #pragma unroll
  for (int i = 0; i < 8; ++i) {
    float s = 0.f;
    s = fmaf(fast_tanh(acc[i][0] + ba.x), wsa.x, s);
    s = fmaf(fast_tanh(acc[i][1] + ba.y), wsa.y, s);
    s = fmaf(fast_tanh(acc[i][2] + ba.z), wsa.z, s);
    s = fmaf(fast_tanh(acc[i][3] + ba.w), wsa.w, s);
    s = fmaf(fast_tanh(acc[i][4] + bb.x), wsb.x, s);
    s = fmaf(fast_tanh(acc[i][5] + bb.y), wsb.y, s);
    s = fmaf(fast_tanh(acc[i][6] + bb.z), wsb.z, s);
    s = fmaf(fast_tanh(acc[i][7] + bb.w), wsb.w, s);
    s_acc[i] = s;
  }
  // reduce across the 8 hq groups (masks 8,16,32)
  #pragma unroll
  for (int m = 8; m < 64; m <<= 1) {
    #pragma unroll
    for (int i = 0; i < 8; ++i) s_acc[i] += __shfl_xor(s_acc[i], m, 64);
  }
  if (hq == 0) {
    #pragma unroll
    for (int i = 0; i < 8; ++i) redsm[wave][rq + 8 * i] = s_acc[i];
  }
  __syncthreads();
  if (tid < 64) {
    float z = redsm[0][tid] + redsm[1][tid] + redsm[2][tid] + redsm[3][tid];
    float sp = fmaxf(z, 0.f) + log1pf(expf(-fabsf(z)));  // stable softplus
    sal_out[rowbase + tid] = sp;
  }
}

// ---------------------------------------------------------------------------
// Kernel 2: per-batch selector. y_star + cumsum + exact top-64
// (desc value, ties -> lower index). Top-64: each wave builds the exact
// sorted top-64 of its 1024-quarter (registers + bitmask, shuffle-only, NO
// barriers), then one thread 4-way-merges the sorted lists (64 steps).
// ---------------------------------------------------------------------------
__global__ __launch_bounds__(256) void k_sel(const float* __restrict__ logt,
    float* __restrict__ ysr, int* __restrict__ topidx,
    float* __restrict__ topsal, float* __restrict__ topcums)
{
  __shared__ float sal[TT];
  __shared__ float ya[TT];   // y (pre-refractory), then reused as cumsum
  __shared__ float yb[TT];   // y_star
  __shared__ float redf[8];
  __shared__ float wl_val[4][KEFF];
  __shared__ int   wl_idx[4][KEFF];

  const int tid = threadIdx.x;
  const int lane = tid & 63;
  const int wave = tid >> 6;
  const int b = blockIdx.x;
  float* row = ysr + (long)b * TT;

  for (int i = tid; i < TT; i += 256) sal[i] = row[i];
  __syncthreads();

  float temp = expf(logt[0]);
  temp = fminf(fmaxf(temp, 0.1f), 10.f);
  const float inv2lam = 1.0f / (2.0f * LAM_);

  for (int i = tid; i < TT; i += 256) {
    float z = (sal[i] * inv2lam - 0.5f) / temp;
    float s;
    if (z >= 0.f) { float e = expf(-z); s = 1.f / (1.f + e); }
    else          { float e = expf(z);  s = e / (1.f + e); }
    ya[i] = (i == 0) ? 0.f : s;
  }
  __syncthreads();

  float loc = 0.f;
  for (int i = tid; i < TT; i += 256) loc += ya[i];
  #pragma unroll
  for (int m = 1; m < 64; m <<= 1) loc += __shfl_xor(loc, m, 64);
  if (lane == 0) redf[wave] = loc;
  __syncthreads();
  float budget = redf[0] + redf[1] + redf[2] + redf[3];
  float scale = fminf(KBUDGET / fmaxf(budget, 1e-6f), 1.f);

  for (int i = tid; i < TT; i += 256) {
    float yi = ya[i] * scale;
    float yj = ya[(i + 1) & (TT - 1)] * scale;
    float m = fminf(2.f / (1.f + (yi + yj)), 1.f);
    yb[i] = (i == 0) ? 0.f : yi * m;
  }
  __syncthreads();

  for (int i = tid; i < TT; i += 256) row[i] = yb[i];   // y_star out

  // inclusive cumsum of saliency into ya
  const int base = tid * 16;
  float run = 0.f;
  #pragma unroll
  for (int j = 0; j < 16; ++j) { run += sal[base + j]; ya[base + j] = run; }
  float v = run;
  #pragma unroll
  for (int m = 1; m < 64; m <<= 1) {
    float u = __shfl_up(v, (unsigned)m, 64);
    if (lane >= m) v += u;
  }
  float lexcl = v - run;
  if (lane == 63) redf[4 + wave] = v;
  __syncthreads();
  float woff = 0.f;
  for (int w = 0; w < wave; ++w) woff += redf[4 + w];
  float off = woff + lexcl;
  #pragma unroll
  for (int j = 0; j < 16; ++j) ya[base + j] += off;
  __syncthreads();

  // per-wave exact sorted top-64 of its quarter (no barriers)
  const int qb = wave * 1024 + lane * 16;
  float lv[16];
  #pragma unroll
  for (int j = 0; j < 16; ++j) lv[j] = yb[qb + j];
  unsigned rm = 0;
  float bv = -1.f; int bi = 1 << 30;
  #pragma unroll
  for (int j = 0; j < 16; ++j)
    if (lv[j] > bv) { bv = lv[j]; bi = qb + j; }

  for (int it = 0; it < KEFF; ++it) {
    float cv = bv; int ci = bi;
    #pragma unroll
    for (int m = 1; m < 64; m <<= 1) {
      float ov = __shfl_xor(cv, m, 64);
      int   oi = __shfl_xor(ci, m, 64);
      if (ov > cv || (ov == cv && oi < ci)) { cv = ov; ci = oi; }
    }
    if (lane == 0) { wl_val[wave][it] = cv; wl_idx[wave][it] = ci; }
    if (ci >= qb && ci < qb + 16) {
      rm |= 1u << (ci - qb);
      bv = -1.f; bi = 1 << 30;
      #pragma unroll
      for (int j = 0; j < 16; ++j)
        if (!((rm >> j) & 1u) && lv[j] > bv) { bv = lv[j]; bi = qb + j; }
    }
  }
  __syncthreads();

  // 4-way merge of sorted lists (val desc, idx asc); quarters have disjoint,
  // increasing index ranges so the tournament's tie-break is globally exact.
  if (tid == 0) {
    int p0 = 0, p1 = 0, p2 = 0, p3 = 0;
    float v0 = wl_val[0][0], v1 = wl_val[1][0], v2 = wl_val[2][0], v3 = wl_val[3][0];
    int   i0 = wl_idx[0][0], i1 = wl_idx[1][0], i2 = wl_idx[2][0], i3 = wl_idx[3][0];
    for (int it = 0; it < KEFF; ++it) {
      float va = v0; int ia = i0; int sa = 0;
      if (v1 > va || (v1 == va && i1 < ia)) { va = v1; ia = i1; sa = 1; }
      if (v2 > va || (v2 == va && i2 < ia)) { va = v2; ia = i2; sa = 2; }
      if (v3 > va || (v3 == va && i3 < ia)) { va = v3; ia = i3; sa = 3; }
      topidx[b * KEFF + it]  = ia;
      topsal[b * KEFF + it]  = sal[ia];
      topcums[b * KEFF + it] = ya[ia];
      if      (sa == 0) { ++p0; v0 = (p0 < KEFF) ? wl_val[0][p0] : -1.f; i0 = (p0 < KEFF) ? wl_idx[0][p0] : (1 << 30); }
      else if (sa == 1) { ++p1; v1 = (p1 < KEFF) ? wl_val[1][p1] : -1.f; i1 = (p1 < KEFF) ? wl_idx[1][p1] : (1 << 30); }
      else if (sa == 2) { ++p2; v2 = (p2 < KEFF) ? wl_val[2][p2] : -1.f; i2 = (p2 < KEFF) ? wl_idx[2][p2] : (1 << 30); }
      else              { ++p3; v3 = (p3 < KEFF) ? wl_val[3][p3] : -1.f; i3 = (p3 < KEFF) ? wl_idx[3][p3] : (1 << 30); }
    }
  }
}

// ---------------------------------------------------------------------------
// Kernel 3: lift + L2-normalize + project for the 2048 selected anchors.
// (round-1 form: 256 blocks x 8 anchors, 256 threads)
// ---------------------------------------------------------------------------
__global__ __launch_bounds__(256) void k_tok(const float* __restrict__ x,
    const float* __restrict__ W_lift, const float* __restrict__ b_lift,
    const float* __restrict__ W_proj, const float* __restrict__ b_proj,
    const int* __restrict__ topidx, const float* __restrict__ topsal,
    const float* __restrict__ topcums, float* __restrict__ tokens)
{
  __shared__ float cloud[8][KL];
  const int tid = threadIdx.x;
  const int k = tid & 63;
  const int g = tid >> 6;
  const int b = blockIdx.x >> 3;
  const int nb = (blockIdx.x & 7) * 8;

  #pragma unroll
  for (int a = 0; a < 2; ++a) {
    int n = nb + g + a * 4;
    int t = topidx[b * KEFF + n];
    const float* xr = x + ((long)b * TT + t) * DD;
    float acc = 0.f;
    #pragma unroll 8
    for (int d4 = 0; d4 < DD / 4; ++d4) {
      float4 xv = *(const float4*)&xr[d4 * 4];
      acc = fmaf(xv.x, W_lift[(d4 * 4 + 0) * KL + k], acc);
      acc = fmaf(xv.y, W_lift[(d4 * 4 + 1) * KL + k], acc);
      acc = fmaf(xv.z, W_lift[(d4 * 4 + 2) * KL + k], acc);
      acc = fmaf(xv.w, W_lift[(d4 * 4 + 3) * KL + k], acc);
    }
    float s  = topsal[b * KEFF + n];
    float tp = (float)t / (float)TT;
    float cm = topcums[b * KEFF + n];
    acc = fmaf(s,  W_lift[128 * KL + k], acc);
    acc = fmaf(tp, W_lift[129 * KL + k], acc);
    acc = fmaf(cm, W_lift[130 * KL + k], acc);
    acc += b_lift[k];
    float ss = acc * acc;
    #pragma unroll
    for (int m = 1; m < 64; m <<= 1) ss += __shfl_xor(ss, m, 64);
    float denom = fmaxf(sqrtf(ss), 1e-6f);
    cloud[g + a * 4][k] = acc / denom;
  }
  __syncthreads();

  #pragma unroll
  for (int q = 0; q < 4; ++q) {
    int dcol = tid + q * 256;
    float accp[8];
    #pragma unroll
    for (int n = 0; n < 8; ++n) accp[n] = 0.f;
    for (int kk = 0; kk < KL; ++kk) {
      float w = W_proj[kk * DM + dcol];
      #pragma unroll
      for (int n = 0; n < 8; ++n) accp[n] = fmaf(cloud[n][kk], w, accp[n]);
    }
    float bp = b_proj[dcol];
    #pragma unroll
    for (int n = 0; n < 8; ++n)
      tokens[((long)b * KEFF + nb + n) * DM + dcol] = accp[n] + bp;
  }
}

extern "C" void kernel_launch(void* const* d_in, const int* in_sizes, int n_in,
                              void* d_out, int out_size, void* d_ws, size_t ws_size,
                              hipStream_t stream) {
  const float* x      = (const float*)d_in[0];
  const float* W1     = (const float*)d_in[1];
  const float* b1     = (const float*)d_in[2];
  // d_in[3] = w_e: event_scores are unused downstream -> skipped entirely
  const float* w_s    = (const float*)d_in[4];
  const float* W_lift = (const float*)d_in[5];
  const float* b_lift = (const float*)d_in[6];
  const float* W_proj = (const float*)d_in[7];
  const float* b_proj = (const float*)d_in[8];
  const float* logt   = (const float*)d_in[9];

  float* tokens = (float*)d_out;
  float* ysr    = tokens + (size_t)BB * KEFF * DM;   // y_star region (also
                                                     // scratch for saliency)
  int*   topidx  = (int*)d_ws;
  float* topsal  = (float*)((char*)d_ws + 8192);
  float* topcums = (float*)((char*)d_ws + 16384);

  k_sal<<<(BB * TT) / 64, 256, 0, stream>>>(x, W1, b1, w_s, ysr);
  k_sel<<<BB, 256, 0, stream>>>(logt, ysr, topidx, topsal, topcums);
  k_tok<<<BB * 8, 256, 0, stream>>>(x, W_lift, b_lift, W_proj, b_proj,
                                    topidx, topsal, topcums, tokens);
}